// Round 5
// baseline (427.090 us; speedup 1.0000x reference)
//
#include <hip/hip_runtime.h>
#include <hip/hip_bf16.h>

// Problem constants
constexpr int NV = 1024;   // vocab
constexpr int NH = 8;      // heads
constexpr int NB = 8;      // batch
constexpr int NT = 1024;   // seq len
constexpr int ND = NV * NH; // 8192 = value dim

typedef __bf16 bf16x8 __attribute__((ext_vector_type(8)));
typedef __bf16 bf16x4 __attribute__((ext_vector_type(4)));
typedef float f32x4 __attribute__((ext_vector_type(4)));

// ---------------- histogram: cnt[b][v] = #positions in batch b with token v ----
__global__ __launch_bounds__(256) void hist_kernel(const int* __restrict__ tok,
                                                   int* __restrict__ cnt) {
    int idx = blockIdx.x * 256 + threadIdx.x;   // 0 .. NB*NT-1
    int b = idx >> 10;
    int t = tok[idx];
    atomicAdd(&cnt[(b << 10) + t], 1);
}

// ---------------- W'[b][t][u] = cnt_b[u]*exp(h[t][u])/Z + (u==t), bf16 ---------
__global__ __launch_bounds__(256) void wprime_kernel(const float* __restrict__ h,
                                                     const int* __restrict__ cnt,
                                                     __bf16* __restrict__ wp) {
    int bt = blockIdx.x;                 // b*1024 + t
    int b = bt >> 10, t = bt & 1023;
    const float4* hrow = (const float4*)(h + (size_t)t * NV);
    const int4* crow = (const int4*)(cnt + (b << 10));
    float4 hv = hrow[threadIdx.x];
    int4 cv = crow[threadIdx.x];
    float e0 = __expf(hv.x) * (float)cv.x;
    float e1 = __expf(hv.y) * (float)cv.y;
    float e2 = __expf(hv.z) * (float)cv.z;
    float e3 = __expf(hv.w) * (float)cv.w;
    float s = (e0 + e1) + (e2 + e3);
#pragma unroll
    for (int off = 32; off > 0; off >>= 1) s += __shfl_down(s, off, 64);
    __shared__ float wsum[4];
    if ((threadIdx.x & 63) == 0) wsum[threadIdx.x >> 6] = s;
    __syncthreads();
    float rz = 1.0f / (wsum[0] + wsum[1] + wsum[2] + wsum[3]);
    int u0 = threadIdx.x << 2;
    float w0 = e0 * rz + (u0 + 0 == t ? 1.0f : 0.0f);
    float w1 = e1 * rz + (u0 + 1 == t ? 1.0f : 0.0f);
    float w2 = e2 * rz + (u0 + 2 == t ? 1.0f : 0.0f);
    float w3 = e3 * rz + (u0 + 3 == t ? 1.0f : 0.0f);
    bf16x4 pk = {(__bf16)w0, (__bf16)w1, (__bf16)w2, (__bf16)w3};
    *(bf16x4*)(wp + (size_t)bt * NV + u0) = pk;
}

// ---------------- vwT[d][k] = (bf16) vw[k][d]  (ND x NV) ------------------------
// 64x64 tile via LDS; bf16x8 (16B) coalesced writes, 128B per output row chunk.
__global__ __launch_bounds__(256) void tcast_kernel(const float* __restrict__ vw,
                                                    __bf16* __restrict__ vwT) {
    __shared__ float tile[64][65];
    int k0 = blockIdx.x << 6;      // 16 blocks
    int d0 = blockIdx.y << 6;      // 128 blocks
    int t = threadIdx.x;
    int kr = t >> 4;               // 0..15
    int dc = (t & 15) << 2;        // 0..60
#pragma unroll
    for (int s = 0; s < 4; ++s) {
        float4 v = *(const float4*)(vw + (size_t)(k0 + kr + 16 * s) * ND + d0 + dc);
        tile[kr + 16 * s][dc + 0] = v.x;
        tile[kr + 16 * s][dc + 1] = v.y;
        tile[kr + 16 * s][dc + 2] = v.z;
        tile[kr + 16 * s][dc + 3] = v.w;
    }
    __syncthreads();
    int dl = t >> 3;               // 0..31
    int ch = t & 7;                // 0..7
#pragma unroll
    for (int s = 0; s < 2; ++s) {
        int d = dl + 32 * s;
        bf16x8 o;
#pragma unroll
        for (int u = 0; u < 8; ++u) o[u] = (__bf16)tile[(ch << 3) + u][d];
        *(bf16x8*)(vwT + (size_t)(d0 + d) * NV + k0 + (ch << 3)) = o;
    }
}

// ---------------- GEMM: out[b][i][:] = (W'_b @ vw)[tok[b][i]][:] ----------------
// 256x256 tile, BK=32, 8 waves (2Mx4N), double-buffered LDS = 64 KB/block
// -> 2 blocks/CU (16 waves, 4/SIMD). Rationale (round-4 counters): per-K-tile
// LDS port (~2800 cyc) and MFMA (~2480 cyc) were ADDING, not overlapping,
// because 1 block/CU left only 2 lockstep waves per SIMD. Two anti-phased
// blocks per CU overlap one block's reads/staging/barrier under the other's
// MFMAs.
// LDS layout (BK=32 rows are 64B -> stride conflict, so pack row pairs):
// logical (r, kchunk c in 0..3) stored at phys row r>>1 (128B), chunk
// (c + 4*(r&1)) ^ ((r>>1)&7). Per 16-lane group each bank-chunk is hit
// exactly 2x (free). Staging keeps LINEAR LDS dest (global_load_lds rule);
// the swizzle is applied by inverse-mapping the per-lane GLOBAL source.
// One sync point per K-tile: vmcnt(0) on loads issued a full tile earlier +
// one s_barrier; barrier-free interior (reads -> setprio MFMA).
#define GLD16(src, dst)                                                        \
    __builtin_amdgcn_global_load_lds(                                          \
        (const __attribute__((address_space(1))) void*)(src),                  \
        (__attribute__((address_space(3))) void*)(dst), 16, 0, 0)

__global__ __launch_bounds__(512, 2) void gemm_kernel(
    const __bf16* __restrict__ wp,    // [NB][NV][NV]
    const __bf16* __restrict__ vwT,   // [ND][NV]
    const int* __restrict__ tok,      // [NB][NT]
    float* __restrict__ out) {        // [NB][NT][ND]
    __shared__ __align__(16) __bf16 As[2 * 128 * 64];   // 32 KB (2 bufs)
    __shared__ __align__(16) __bf16 Bs[2 * 128 * 64];   // 32 KB

    // XCD-aware mapping: blocks round-robin across 8 XCDs (blk&7).
    // XCD x owns batch x; within XCD, bm varies fastest (B tile 4-way reuse,
    // A panel wp[b] 2MB L2-resident).
    int blk = blockIdx.x;
    int b = blk & 7;               // XCD id == batch
    int local = blk >> 3;          // 0..127 within XCD
    int bm_l = local & 3;          // fastest: M-tile within batch
    int bn = local >> 2;           // 0..31
    int i0 = bm_l << 8;            // row base within batch
    int n0 = bn << 8;
    int tid = threadIdx.x;

    // staging: per K-tile 1024 16B segs per matrix; thread t handles phys segs
    // t and t+512. Phys seg s -> phys row s>>3, phys chunk s&7. Inverse swizzle
    // gives the logical source: u = (s&7) ^ ((s>>3)&7); logical row =
    // 2*(s>>3) + (u>>2); k-chunk = u&3.  (s>>3)&7 is equal for s and s+512.
    int pr0 = tid >> 3;            // 0..63
    int pc = tid & 7;
    int u = pc ^ (pr0 & 7);
    int lr = (pr0 << 1) + (u >> 2);   // logical row 0..127 (p=1 adds 128)
    int lc = u & 3;                   // k-chunk (8 bf16 each)
    const __bf16* srcA[2];
    const __bf16* srcB[2];
#pragma unroll
    for (int p = 0; p < 2; ++p) {
        int r = lr + 128 * p;     // 0..255
        int tk = tok[(b << 10) + i0 + r];
        srcA[p] = wp + (((size_t)(b << 10) + tk) << 10) + (lc << 3);
        srcB[p] = vwT + ((size_t)(n0 + r) << 10) + (lc << 3);
    }

    int lane = tid & 63;
    int wave = tid >> 6;
    int wm = wave >> 2, wn = wave & 3;   // 2 x 4 wave grid, each 128x64 out
    int quad = lane >> 4;
    int l15 = lane & 15;
    int offA[8], offB[4];
#pragma unroll
    for (int f = 0; f < 8; ++f) {
        int m = (wm << 7) + (f << 4) + l15;
        offA[f] = ((m >> 1) << 6) +
                  (((quad + ((m & 1) << 2)) ^ ((m >> 1) & 7)) << 3);
    }
#pragma unroll
    for (int f = 0; f < 4; ++f) {
        int n = (wn << 6) + (f << 4) + l15;
        offB[f] = ((n >> 1) << 6) +
                  (((quad + ((n & 1) << 2)) ^ ((n >> 1) & 7)) << 3);
    }

    f32x4 acc[8][4];
#pragma unroll
    for (int i = 0; i < 8; ++i)
#pragma unroll
        for (int j = 0; j < 4; ++j) acc[i][j] = (f32x4){0.f, 0.f, 0.f, 0.f};

    __bf16* A0 = As;
    __bf16* A1 = As + 8192;
    __bf16* B0 = Bs;
    __bf16* B1 = Bs + 8192;

    // prologue: issue K-tile 0 into buf0 (first KSTEP's vmcnt(0)+barrier waits)
    GLD16(srcA[0], A0 + (tid << 3));
    GLD16(srcA[1], A0 + ((tid + 512) << 3));
    GLD16(srcB[0], B0 + (tid << 3));
    GLD16(srcB[1], B0 + ((tid + 512) << 3));
    srcA[0] += 32; srcA[1] += 32; srcB[0] += 32; srcB[1] += 32;
    asm volatile("" ::: "memory");

// One K-tile (BK=32): wait stale loads (issued a full tile ago), ONE barrier,
// issue next tile's 4 loads (in flight across the whole tile body), then
// barrier-free interior: 12 ds_read_b128 + 32 MFMA under setprio.
#define KSTEP(Ab, Bb, An, Bn, MORE)                                            \
    {                                                                          \
        asm volatile("s_waitcnt vmcnt(0)" ::: "memory");                       \
        __builtin_amdgcn_s_barrier();                                          \
        if (MORE) {                                                            \
            GLD16(srcA[0], (An) + (tid << 3));                                 \
            GLD16(srcA[1], (An) + ((tid + 512) << 3));                         \
            GLD16(srcB[0], (Bn) + (tid << 3));                                 \
            GLD16(srcB[1], (Bn) + ((tid + 512) << 3));                         \
            srcA[0] += 32; srcA[1] += 32; srcB[0] += 32; srcB[1] += 32;        \
            asm volatile("" ::: "memory");                                     \
        }                                                                      \
        bf16x8 af[8], bf[4];                                                   \
        _Pragma("unroll") for (int f = 0; f < 4; ++f)                          \
            bf[f] = *(const bf16x8*)((Bb) + offB[f]);                          \
        _Pragma("unroll") for (int f = 0; f < 8; ++f)                          \
            af[f] = *(const bf16x8*)((Ab) + offA[f]);                          \
        __builtin_amdgcn_s_setprio(1);                                         \
        _Pragma("unroll") for (int i = 0; i < 8; ++i)                          \
            _Pragma("unroll") for (int j = 0; j < 4; ++j)                      \
                acc[i][j] = __builtin_amdgcn_mfma_f32_16x16x32_bf16(           \
                    af[i], bf[j], acc[i][j], 0, 0, 0);                         \
        __builtin_amdgcn_s_setprio(0);                                         \
    }

#pragma unroll 1
    for (int it = 0; it < 16; ++it) {
        KSTEP(A0, B0, A1, B1, 1);          // even K-tile: compute buf0, stage buf1
        KSTEP(A1, B1, A0, B0, (it < 15));  // odd K-tile: compute buf1, stage buf0
    }

    // epilogue: C/D layout col=lane&15, row=quad*4+reg
    size_t outbase = (((size_t)(b << 10) + i0) << 13) + n0;
#pragma unroll
    for (int fi = 0; fi < 8; ++fi) {
#pragma unroll
        for (int fj = 0; fj < 4; ++fj) {
            int rr0 = (wm << 7) + (fi << 4) + (quad << 2);
            int cw = (wn << 6) + (fj << 4) + l15;
            float* po = out + outbase + ((size_t)rr0 << 13) + cw;
#pragma unroll
            for (int r = 0; r < 4; ++r)
                po[(size_t)r << 13] = acc[fi][fj][r];
        }
    }
}

extern "C" void kernel_launch(void* const* d_in, const int* in_sizes, int n_in,
                              void* d_out, int out_size, void* d_ws, size_t ws_size,
                              hipStream_t stream) {
    const int* tok = (const int*)d_in[0];       // [NB][NT] token ids
    const float* h = (const float*)d_in[1];     // [NV][NV]
    const float* vw = (const float*)d_in[2];    // [NV][ND]
    float* out = (float*)d_out;                 // [NB][NT][ND]

    char* ws = (char*)d_ws;
    int* cnt = (int*)ws;                                    // 32 KB
    __bf16* wp = (__bf16*)(ws + (1 << 16));                 // 16 MB
    __bf16* vwT = (__bf16*)(ws + (1 << 16) +
                            (size_t)NB * NV * NV * 2);      // 16 MB

    (void)hipMemsetAsync(cnt, 0, NB * NV * sizeof(int), stream);
    hist_kernel<<<NB * NT / 256, 256, 0, stream>>>(tok, cnt);
    wprime_kernel<<<NB * NV, 256, 0, stream>>>(h, cnt, wp);
    tcast_kernel<<<dim3(NV / 64, ND / 64), 256, 0, stream>>>(vw, vwT);
    gemm_kernel<<<NB * (NT / 256) * (ND / 256), 512, 0, stream>>>(wp, vwT, tok, out);
}